// Round 9
// baseline (1227.294 us; speedup 1.0000x reference)
//
#include <hip/hip_runtime.h>
#include <hip/hip_bf16.h>
#include <math.h>

#define N_NODES 50000
#define E1 300000
#define EN 30000
#define ETOT 330000

typedef __hip_bfloat16 bf16;
typedef __attribute__((ext_vector_type(8))) short s8v;   // 8 bf16 in 4 VGPRs
typedef __attribute__((ext_vector_type(4))) float f4v;   // MFMA accum

__device__ __forceinline__ float b2f(bf16 x){ return __bfloat162float(x); }
__device__ __forceinline__ bf16 f2b(float x){ return __float2bfloat16(x); }

__device__ __forceinline__ f4v mfma16(s8v a, s8v b, f4v c){
  return __builtin_amdgcn_mfma_f32_16x16x32_bf16(a, b, c, 0, 0, 0);
}

__device__ __forceinline__ float ldf(const void* p, long i, bool f32){
  return f32 ? ((const float*)p)[i] : b2f(((const bf16*)p)[i]);
}
__device__ __forceinline__ void stf(void* p, long i, float v, bool f32){
  if (f32) ((float*)p)[i] = v; else ((bf16*)p)[i] = f2b(v);
}
// packed 4-element store (16B fp32 / 8B bf16), elem must be multiple of 4
__device__ __forceinline__ void stv4(void* p, long elem, float a, float b,
                                     float c, float d, bool f32){
  if (f32){
    float4 t; t.x=a; t.y=b; t.z=c; t.w=d;
    *reinterpret_cast<float4*>((float*)p + elem) = t;
  } else {
    bf16 t[4] = {f2b(a), f2b(b), f2b(c), f2b(d)};
    *reinterpret_cast<uint2*>((bf16*)p + elem) = *reinterpret_cast<uint2*>(t);
  }
}

// Detect input dtype: flag=0 -> bf16, flag=1 -> fp32
__global__ void k_detect(const void* __restrict__ emb, int* __restrict__ flag){
  const unsigned short* h = (const unsigned short*)emb;
  int sane = 0;
  for (int i=0;i<128;i++){
    unsigned e = (h[i]>>7)&0xFFu;
    if (e>=112u && e<=143u) sane++;
  }
  *flag = (sane >= 112) ? 0 : 1;
}

// ---- CSR build (by dst), shared by all 3 edge passes ----
__global__ void k_hist(const int* __restrict__ el, const int* __restrict__ eln,
                       int* __restrict__ cnt){
  int i = blockIdx.x*blockDim.x + threadIdx.x;
  if (i < ETOT){
    int dst = (i < E1) ? el[i] : eln[i - E1];
    atomicAdd(cnt + dst, 1);
  }
}

__global__ __launch_bounds__(1024) void k_scan(const int* __restrict__ cnt,
                                               int* __restrict__ rowp,
                                               int* __restrict__ cur){
  __shared__ int part[1024];
  int t = threadIdx.x;
  const int CH = (N_NODES + 1023)/1024;
  int base = t*CH;
  int s = 0;
  for (int i=0;i<CH;i++){ int n = base+i; if (n < N_NODES) s += cnt[n]; }
  part[t] = s;
  __syncthreads();
  for (int o=1;o<1024;o<<=1){
    int u = (t>=o) ? part[t-o] : 0;
    __syncthreads();
    part[t] += u;
    __syncthreads();
  }
  int off = part[t] - s;
  for (int i=0;i<CH;i++){
    int n = base+i;
    if (n < N_NODES){ rowp[n] = off; cur[n] = off; off += cnt[n]; }
  }
  if (t==0) rowp[N_NODES] = ETOT;
}

__global__ void k_fill(const int* __restrict__ el, const int* __restrict__ et,
                       const int* __restrict__ eln, const int* __restrict__ etn,
                       int* __restrict__ cur, int* __restrict__ esrc,
                       int* __restrict__ epak){
  int i = blockIdx.x*blockDim.x + threadIdx.x;
  if (i >= ETOT) return;
  int dst, src, pk;
  if (i < E1){
    dst = el[i]; src = el[E1 + i];
    pk = et[i];
  } else {
    int e = i - E1;
    dst = eln[e]; src = eln[EN + e];
    pk = etn[2*e] | (etn[2*e+1]<<9) | (1<<18);
  }
  int pos = atomicAdd(cur + dst, 1);
  esrc[pos] = src; epak[pos] = pk;
}

// ---- gather layer-1 (fused fin1): one wave per dst node, float2 lanes ----
__global__ __launch_bounds__(256) void k_gath1(
    const int* __restrict__ rowp, const int* __restrict__ esrc,
    const int* __restrict__ epak,
    const float* __restrict__ pd, const float* __restrict__ ps,
    const float* __restrict__ rp,
    const float* __restrict__ sd, const float* __restrict__ ss,
    const float* __restrict__ sr,
    float* __restrict__ x, int hoff){
  int w = threadIdx.x >> 6, lane = threadIdx.x & 63;
  int n = blockIdx.x*4 + w;
  if (n >= N_NODES) return;
  const float2* ps2 = (const float2*)ps;
  const float2* rp2 = (const float2*)rp;
  float2 acc; acc.x = 0.f; acc.y = 0.f;
  float rs = 0.f;
  float sdn = sd[n];
  int b = rowp[n], e = rowp[n+1];
  for (int i=b;i<e;i++){
    int src = esrc[i], pk = epak[i];
    int t0 = pk & 511, t1 = (pk>>9)&511, has2 = (pk>>18)&1;
    float srv = sr[t0] + (has2 ? sr[t1] : 0.f);
    float score = sdn + ss[src] + srv;
    float lr = score > 0.f ? score : 0.2f*score;
    float wgt = expf(-lr);
    rs += wgt;
    float2 v  = ps2[(long)src*64 + lane];
    float2 r1 = rp2[(long)t0*64 + lane];
    v.x += r1.x; v.y += r1.y;
    if (has2){ float2 r2v = rp2[(long)t1*64 + lane]; v.x += r2v.x; v.y += r2v.y; }
    acc.x += wgt*v.x; acc.y += wgt*v.y;
  }
  float denom = (rs == 0.f) ? 1e-12f : rs;
  float2 pdv = ((const float2*)pd)[(long)n*64 + lane];
  float hr0 = rs*pdv.x + acc.x, hr1 = rs*pdv.y + acc.y;
  float h0 = hr0/denom; h0 = h0 > 0.f ? h0 : (expf(h0) - 1.f);
  float h1 = hr1/denom; h1 = h1 > 0.f ? h1 : (expf(h1) - 1.f);
  float2 o; o.x = h0; o.y = h1;
  *reinterpret_cast<float2*>(x + (long)n*256 + hoff + lane*2) = o;
}

// ---- gather layer-2 (fused final epilogue): float4 lanes ----
__global__ __launch_bounds__(256) void k_gath2(
    const int* __restrict__ rowp, const int* __restrict__ esrc,
    const int* __restrict__ epak,
    const float* __restrict__ p2d, const float* __restrict__ ps,
    const float* __restrict__ rp,
    const float* __restrict__ sd, const float* __restrict__ ss,
    const float* __restrict__ sr,
    const float* __restrict__ eu, const float* __restrict__ mask,
    const int* __restrict__ flag, void* __restrict__ out){
  bool f32 = flag[0] != 0;
  int w = threadIdx.x >> 6, lane = threadIdx.x & 63;
  int n = blockIdx.x*4 + w;
  if (n >= N_NODES) return;
  const float4* ps4 = (const float4*)ps;
  const float4* rp4 = (const float4*)rp;
  float4 acc; acc.x=acc.y=acc.z=acc.w=0.f;
  float rs = 0.f;
  float sdn = sd[n];
  int b = rowp[n], e = rowp[n+1];
  for (int i=b;i<e;i++){
    int src = esrc[i], pk = epak[i];
    int t0 = pk & 511, t1 = (pk>>9)&511, has2 = (pk>>18)&1;
    float srv = sr[t0] + (has2 ? sr[t1] : 0.f);
    float score = sdn + ss[src] + srv;
    float lr = score > 0.f ? score : 0.2f*score;
    float wgt = expf(-lr);
    rs += wgt;
    float4 v  = ps4[(long)src*64 + lane];
    float4 r1 = rp4[(long)t0*64 + lane];
    v.x += r1.x; v.y += r1.y; v.z += r1.z; v.w += r1.w;
    if (has2){
      float4 r2v = rp4[(long)t1*64 + lane];
      v.x += r2v.x; v.y += r2v.y; v.z += r2v.z; v.w += r2v.w;
    }
    acc.x += wgt*v.x; acc.y += wgt*v.y; acc.z += wgt*v.z; acc.w += wgt*v.w;
  }
  float denom = (rs == 0.f) ? 1e-12f : rs;
  float mk = mask[n];
  float4 pdv = ((const float4*)p2d)[(long)n*64 + lane];
  float4 euv = ((const float4*)eu)[(long)n*64 + lane];
  float av[4] = {acc.x, acc.y, acc.z, acc.w};
  float pv[4] = {pdv.x, pdv.y, pdv.z, pdv.w};
  float ev[4] = {euv.x, euv.y, euv.z, euv.w};
  float val[4], xl[4];
  float n1 = 0.f, n2 = 0.f;
  #pragma unroll
  for (int m=0;m<4;m++){
    float hr = rs*pv[m] + av[m];
    float xo = hr/denom; xo = xo > 0.f ? xo : (expf(xo) - 1.f);
    float l  = hr > 0.f ? hr : (expf(hr) - 1.f);
    float v  = ev[m] + mk*xo;
    val[m] = v; xl[m] = l;
    n1 += v*v; n2 += l*l;
  }
  #pragma unroll
  for (int o=32;o>0;o>>=1){ n1 += __shfl_xor(n1,o); n2 += __shfl_xor(n2,o); }
  float i1 = 1.f/fmaxf(sqrtf(n1), 1e-12f);
  float i2 = 1.f/fmaxf(sqrtf(n2), 1e-12f);
  stv4(out, (long)n*256 + lane*4,
       val[0]*i1, val[1]*i1, val[2]*i1, val[3]*i1, f32);
  stv4(out, 12865536L + (long)n*256 + lane*4,
       xl[0]*i2, xl[1]*i2, xl[2]*i2, xl[3]*i2, f32);
}

// out_relation_1 = rel @ W  (fp32 copy to ws + dual-dtype output at element offset)
__global__ void k_rel2(const void* __restrict__ rel, const void* __restrict__ W,
                       const int* __restrict__ flag,
                       float* __restrict__ r2, void* __restrict__ out){
  bool f32 = flag[0] != 0;
  int t = blockIdx.x, j = threadIdx.x;   // 256 threads
  __shared__ float rs_[128];
  if (j < 128) rs_[j] = ldf(rel, (long)t*128 + j, f32);
  __syncthreads();
  float acc = 0.f;
  #pragma unroll 4
  for (int k=0;k<128;k++) acc += rs_[k]*ldf(W, (long)k*256 + j, f32);
  r2[(long)t*256+j] = acc;
  stf(out, 12800000L + (long)t*256 + j, acc, f32);
}

// Transpose weight block to fp32 [k][J]: dst[k*J+j] = src[bias + j*jstride + k]
__global__ void k_trF(const void* __restrict__ src, const int* __restrict__ flag,
                      long bias, long jstride, int J, float* __restrict__ dst){
  bool f32 = flag[0] != 0;
  int k = blockIdx.x, j = threadIdx.x;
  dst[(long)k*J + j] = ldf(src, bias + (long)j*jstride + k, f32);
}

// Weight fragment pack for MFMA: [col][k] bf16 hi/lo split.
// whi[c*K+k] = bf16(w), wlo[c*K+k] = bf16(w - float(whi))
__global__ void k_wfrag(const void* __restrict__ src, const int* __restrict__ flag,
                        long bias, long jstride, int K,
                        bf16* __restrict__ whi, bf16* __restrict__ wlo){
  bool f32 = flag[0] != 0;
  int c = blockIdx.x, k = threadIdx.x;
  float w = ldf(src, bias + (long)c*jstride + k, f32);
  bf16 h = f2b(w);
  whi[(long)c*K + k] = h;
  wlo[(long)c*K + k] = f2b(w - b2f(h));
}

// Convert-only (no transpose) to fp32: dst[i] = src[i]
__global__ void k_cvtF(const void* __restrict__ src, const int* __restrict__ flag,
                       int n, float* __restrict__ dst){
  bool f32 = flag[0] != 0;
  int i = blockIdx.x*blockDim.x + threadIdx.x;
  if (i < n) dst[i] = ldf(src, i, f32);
}

// ---- MFMA layer-2 node projection (split-bf16, 3-term) ----
// Per block: 64 rows, 4 waves x 16 rows. Per wave: 16 col-tiles x 2 mats,
// K=256 in 8 kblks of 32. A-frags from XOR-swizzled LDS (hi/lo bf16);
// B-frags from fragment-packed [col][k] weights. Fused a2-score epilogue.
// Layouts (verified, learn_hip m89/m91): C/D col=lane&15,row=(lane>>4)*4+r;
// A row=lane&15, k=(lane>>4)*8+j; B col=lane&15, k=(lane>>4)*8+j.
__global__ __launch_bounds__(256) void k_gm2(
    const float* __restrict__ X, int N,
    const bf16* __restrict__ whd, const bf16* __restrict__ wld,
    const bf16* __restrict__ whs, const bf16* __restrict__ wls,
    const void* __restrict__ a2, const int* __restrict__ flag,
    float* __restrict__ O1, float* __restrict__ O2,
    float* __restrict__ s1, float* __restrict__ s2){
  __shared__ __align__(16) bf16 xhi[64*256];
  __shared__ __align__(16) bf16 xlo[64*256];
  int t = threadIdx.x, wv = t>>6, ln = t&63;
  int n0 = blockIdx.x*64;

  // stage + hi/lo split, XOR-swizzled ((row&7)<<4 on byte addr)
  for (int i = t; i < 64*64; i += 256){
    int row = i >> 6, kq = i & 63;
    int n = n0 + row;
    float4 v; v.x=v.y=v.z=v.w=0.f;
    if (n < N) v = *reinterpret_cast<const float4*>(X + (long)n*256 + kq*4);
    bf16 h[4], l[4];
    h[0]=f2b(v.x); l[0]=f2b(v.x-b2f(h[0]));
    h[1]=f2b(v.y); l[1]=f2b(v.y-b2f(h[1]));
    h[2]=f2b(v.z); l[2]=f2b(v.z-b2f(h[2]));
    h[3]=f2b(v.w); l[3]=f2b(v.w-b2f(h[3]));
    long byo = ((long)row*512 + kq*8) ^ ((row&7)<<4);
    *reinterpret_cast<uint2*>(reinterpret_cast<char*>(xhi)+byo) =
        *reinterpret_cast<const uint2*>(h);
    *reinterpret_cast<uint2*>(reinterpret_cast<char*>(xlo)+byo) =
        *reinterpret_cast<const uint2*>(l);
  }
  __syncthreads();

  int cl = ln & 15, rg = ln >> 4;
  long arow = (long)(wv*16 + cl);
  long abase = arow*512 + rg*16;
  long aswz = (arow&7)<<4;
  const char* xh = reinterpret_cast<const char*>(xhi);
  const char* xl = reinterpret_cast<const char*>(xlo);

  f4v accd[16], accs[16];
  const f4v zf = {0.f,0.f,0.f,0.f};
  #pragma unroll
  for (int ct=0; ct<16; ++ct){ accd[ct]=zf; accs[ct]=zf; }

  #pragma unroll 1
  for (int kb=0; kb<8; ++kb){
    s8v ah = *reinterpret_cast<const s8v*>(xh + ((abase + kb*64) ^ aswz));
    s8v al = *reinterpret_cast<const s8v*>(xl + ((abase + kb*64) ^ aswz));
    long kO = kb*32 + rg*8;
    #pragma unroll
    for (int ct=0; ct<16; ++ct){
      long wo = (long)(ct*16 + cl)*256 + kO;
      s8v bh = *reinterpret_cast<const s8v*>((const void*)(whd + wo));
      s8v bl = *reinterpret_cast<const s8v*>((const void*)(wld + wo));
      accd[ct] = mfma16(ah, bh, accd[ct]);
      accd[ct] = mfma16(ah, bl, accd[ct]);
      accd[ct] = mfma16(al, bh, accd[ct]);
      s8v ch  = *reinterpret_cast<const s8v*>((const void*)(whs + wo));
      s8v cl2 = *reinterpret_cast<const s8v*>((const void*)(wls + wo));
      accs[ct] = mfma16(ah, ch,  accs[ct]);
      accs[ct] = mfma16(ah, cl2, accs[ct]);
      accs[ct] = mfma16(al, ch,  accs[ct]);
    }
  }

  // fused scores: s1[n]=dot(O1[n,:],a2), s2[n]=dot(O2[n,:],a2)
  bool af32 = flag[0] != 0;
  float sc1[4]={0.f,0.f,0.f,0.f}, sc2[4]={0.f,0.f,0.f,0.f};
  #pragma unroll
  for (int ct=0; ct<16; ++ct){
    float a2v = ldf(a2, ct*16 + cl, af32);
    #pragma unroll
    for (int r=0;r<4;r++){ sc1[r] += accd[ct][r]*a2v; sc2[r] += accs[ct][r]*a2v; }
  }
  #pragma unroll
  for (int r=0;r<4;r++){
    int n = n0 + wv*16 + rg*4 + r;
    if (n < N){
      #pragma unroll
      for (int ct=0; ct<16; ++ct){
        O1[(long)n*256 + ct*16 + cl] = accd[ct][r];
        O2[(long)n*256 + ct*16 + cl] = accs[ct][r];
      }
    }
  }
  #pragma unroll
  for (int o=1;o<16;o<<=1){
    #pragma unroll
    for (int r=0;r<4;r++){
      sc1[r] += __shfl_xor(sc1[r], o);
      sc2[r] += __shfl_xor(sc2[r], o);
    }
  }
  if (cl == 0){
    #pragma unroll
    for (int r=0;r<4;r++){
      int n = n0 + wv*16 + rg*4 + r;
      if (n < N){ s1[n] = sc1[r]; s2[n] = sc2[r]; }
    }
  }
}

// Unified scalar GEMM kernel (layer-1 / relation / entup paths)
template<int NT, int K, int KT, int BM, int NCOL, int COLS_TOT,
         int NORM, int DUAL, int SCORE, int XDUAL>
__global__ __launch_bounds__(NT) void k_gnp(
    const void* __restrict__ X, const int* __restrict__ flag, int N,
    const float* __restrict__ WT1, const float* __restrict__ WT2,
    const void* __restrict__ a2, long a2bias,
    float* __restrict__ O1, float* __restrict__ O2,
    float* __restrict__ s1, float* __restrict__ s2){
  const int COLS  = 64*NCOL;
  const int WAVES = NT/64;
  const int RW    = BM/WAVES;
  __shared__ __align__(16) float xs[BM][KT];
  __shared__ float rsc[BM];
  int t = threadIdx.x;
  int wv = t >> 6, ln = t & 63;
  int r0 = wv * RW;
  int n0 = blockIdx.x * BM;
  int coff = blockIdx.y * COLS;
  bool xf32 = XDUAL ? (flag[0] != 0) : true;

  float a1c[RW][NCOL], a2c[RW][NCOL];
  #pragma unroll
  for (int m=0;m<RW;m++)
    #pragma unroll
    for (int c=0;c<NCOL;c++){ a1c[m][c]=0.f; a2c[m][c]=0.f; }

  for (int kt0 = 0; kt0 < K; kt0 += KT){
    if (xf32){
      const int KQ = KT/4;
      for (int idx = t; idx < BM*KQ; idx += NT){
        int m = idx / KQ, kq = idx - m*KQ;
        int n = n0 + m;
        float4 v; v.x=v.y=v.z=v.w=0.f;
        if (n < N)
          v = *reinterpret_cast<const float4*>((const float*)X + (long)n*K + kt0 + kq*4);
        *reinterpret_cast<float4*>(&xs[m][kq*4]) = v;
      }
    } else {
      for (int idx = t; idx < BM*KT; idx += NT){
        int m = idx / KT, k = idx - m*KT;
        int n = n0 + m;
        xs[m][k] = (n < N) ? b2f(((const bf16*)X)[(long)n*K + kt0 + k]) : 0.f;
      }
    }
    __syncthreads();

    if (NORM){
      const int NPR = NT / BM;
      int r = t / NPR, l = t - r*NPR;
      float ssq = 0.f;
      #pragma unroll
      for (int k = l; k < KT; k += NPR){ float v = xs[r][k]; ssq += v*v; }
      #pragma unroll
      for (int o = NPR>>1; o > 0; o >>= 1) ssq += __shfl_xor(ssq, o);
      if (l == 0) rsc[r] = 1.f / fmaxf(sqrtf(ssq), 1e-12f);
      __syncthreads();
      for (int idx = t; idx < BM*KT; idx += NT){
        int m = idx / KT, k = idx - m*KT;
        xs[m][k] *= rsc[m];
      }
      __syncthreads();
    }

    #pragma unroll 1
    for (int k0=0;k0<KT;k0+=4){
      float w1v[4][NCOL], w2v[4][NCOL];
      #pragma unroll
      for (int i=0;i<4;i++){
        const float* p1 = WT1 + (long)(kt0+k0+i)*COLS_TOT + coff + ln*NCOL;
        if constexpr (NCOL==4){
          float4 v = *reinterpret_cast<const float4*>(p1);
          w1v[i][0]=v.x; w1v[i][1]=v.y; w1v[i][2]=v.z; w1v[i][3]=v.w;
        } else {
          float2 v = *reinterpret_cast<const float2*>(p1);
          w1v[i][0]=v.x; w1v[i][1]=v.y;
        }
        if (DUAL){
          const float* p2 = WT2 + (long)(kt0+k0+i)*COLS_TOT + coff + ln*NCOL;
          if constexpr (NCOL==4){
            float4 v = *reinterpret_cast<const float4*>(p2);
            w2v[i][0]=v.x; w2v[i][1]=v.y; w2v[i][2]=v.z; w2v[i][3]=v.w;
          } else {
            float2 v = *reinterpret_cast<const float2*>(p2);
            w2v[i][0]=v.x; w2v[i][1]=v.y;
          }
        }
      }
      #pragma unroll
      for (int m=0;m<RW;m++){
        float4 xv = *reinterpret_cast<const float4*>(&xs[r0+m][k0]);
        #pragma unroll
        for (int c=0;c<NCOL;c++){
          a1c[m][c] += xv.x*w1v[0][c] + xv.y*w1v[1][c] + xv.z*w1v[2][c] + xv.w*w1v[3][c];
          if (DUAL)
            a2c[m][c] += xv.x*w2v[0][c] + xv.y*w2v[1][c] + xv.z*w2v[2][c] + xv.w*w2v[3][c];
        }
      }
    }
    __syncthreads();
  }

  #pragma unroll
  for (int m=0;m<RW;m++){
    int n = n0 + r0 + m;
    if (n < N){
      float* o1 = O1 + (long)n*COLS_TOT + coff + ln*NCOL;
      if constexpr (NCOL==4){
        float4 v; v.x=a1c[m][0]; v.y=a1c[m][1]; v.z=a1c[m][2]; v.w=a1c[m][3];
        *reinterpret_cast<float4*>(o1) = v;
      } else {
        float2 v; v.x=a1c[m][0]; v.y=a1c[m][1];
        *reinterpret_cast<float2*>(o1) = v;
      }
      if (DUAL){
        float* o2 = O2 + (long)n*COLS_TOT + coff + ln*NCOL;
        if constexpr (NCOL==4){
          float4 v; v.x=a2c[m][0]; v.y=a2c[m][1]; v.z=a2c[m][2]; v.w=a2c[m][3];
          *reinterpret_cast<float4*>(o2) = v;
        } else {
          float2 v; v.x=a2c[m][0]; v.y=a2c[m][1];
          *reinterpret_cast<float2*>(o2) = v;
        }
      }
    }
  }

  if (SCORE){
    bool af32 = flag[0] != 0;
    float a2v[NCOL];
    #pragma unroll
    for (int c=0;c<NCOL;c++) a2v[c] = ldf(a2, a2bias + coff + ln*NCOL + c, af32);
    long soff = (long)blockIdx.y * N;
    #pragma unroll
    for (int m=0;m<RW;m++){
      float v1 = 0.f, v2 = 0.f;
      #pragma unroll
      for (int c=0;c<NCOL;c++){
        v1 += a1c[m][c]*a2v[c];
        if (DUAL) v2 += a2c[m][c]*a2v[c];
      }
      #pragma unroll
      for (int o=32;o>0;o>>=1){
        v1 += __shfl_down(v1,o);
        if (DUAL) v2 += __shfl_down(v2,o);
      }
      int n = n0 + r0 + m;
      if (ln==0 && n < N){
        s1[soff + n] = v1;
        if (DUAL) s2[soff + n] = v2;
      }
    }
  }
}

__global__ void k_mask(const int* __restrict__ bi, float* __restrict__ mask){
  int i = blockIdx.x*blockDim.x + threadIdx.x;
  if (i < 4096) mask[bi[i*3 + 2]] = 1.f;
}

extern "C" void kernel_launch(void* const* d_in, const int* in_sizes, int n_in,
                              void* d_out, int out_size, void* d_ws, size_t ws_size,
                              hipStream_t stream) {
  const void* emb = d_in[0];
  const void* rel = d_in[1];
  const void* a1b = d_in[2];
  const void* a21 = d_in[3];
  const void* W   = d_in[4];
  const void* aout= d_in[5];
  const void* a2o = d_in[6];
  const void* We  = d_in[7];
  const int* bi   = (const int*)d_in[8];
  const int* el   = (const int*)d_in[9];
  const int* et   = (const int*)d_in[10];
  const int* eln  = (const int*)d_in[11];
  const int* etn  = (const int*)d_in[12];
  float* ws = (float*)d_ws;

  const size_t PD_=0, PS_=6400000;
  const size_t P2D_=0;
  const size_t CNT_=12800000, ROWP_=12860000, ESRC_=12920000, EPAK_=13260000;
  const size_t TW_=19200000;
  const size_t X_=25600000;        // x, later eu
  const size_t P2S_=38400000;
  const size_t SD_=51250000, SS_=51300000, S2D_=51350000,
               S2S_=51400000, MK_=51500000,
               RP1_=51550000, SR1_=51590000, R2_=51600000, RP2_=51670000,
               SR2_=51740000, FLAG_=51750000;
  int* flag = (int*)(ws + FLAG_);
  int* cnt  = (int*)(ws + CNT_);
  int* rowp = (int*)(ws + ROWP_);
  int* esrc = (int*)(ws + ESRC_);
  int* epak = (int*)(ws + EPAK_);

  k_detect<<<1,1,0,stream>>>(emb, flag);

  hipMemsetAsync(ws+MK_,  0, (size_t)50000*sizeof(float), stream);
  hipMemsetAsync(cnt,     0, (size_t)50000*sizeof(int), stream);

  // CSR build (once; shared by all 3 edge passes)
  k_hist<<<(ETOT+255)/256,256,0,stream>>>(el, eln, cnt);
  k_scan<<<1,1024,0,stream>>>(cnt, rowp, cnt);
  k_fill<<<(ETOT+255)/256,256,0,stream>>>(el, et, eln, etn, cnt, esrc, epak);

  // transpose the 6 layer-1 weight blocks to fp32 [k][128]
  k_trF<<<128,128,0,stream>>>(a1b, flag, 0L,          384L, 128, ws+TW_);          // h0 a_d
  k_trF<<<128,128,0,stream>>>(a1b, flag, 128L,        384L, 128, ws+TW_+16384);    // h0 a_s
  k_trF<<<128,128,0,stream>>>(a1b, flag, 49152L,      384L, 128, ws+TW_+32768);    // h1 a_d
  k_trF<<<128,128,0,stream>>>(a1b, flag, 49152L+128L, 384L, 128, ws+TW_+49152);    // h1 a_s
  k_trF<<<128,128,0,stream>>>(a1b, flag, 256L,        384L, 128, ws+TW_+65536);    // h0 a_r
  k_trF<<<128,128,0,stream>>>(a1b, flag, 49152L+256L, 384L, 128, ws+TW_+81920);    // h1 a_r

  // head 0: fused norm + dual projection + score; rel-proj via gnp; gather
  k_gnp<256,128,128,32,2,128,1,1,1,1><<<dim3((N_NODES+31)/32,1),256,0,stream>>>(
      emb, flag, N_NODES, ws+TW_, ws+TW_+16384, a21, 0L,
      ws+PD_, ws+PS_, ws+SD_, ws+SS_);
  k_gnp<256,128,128,64,2,128,0,0,1,1><<<dim3(4,1),256,0,stream>>>(
      rel, flag, 256, ws+TW_+65536, nullptr, a21, 0L,
      ws+RP1_, nullptr, ws+SR1_, nullptr);
  k_gath1<<<(N_NODES+3)/4,256,0,stream>>>(rowp, esrc, epak,
      ws+PD_, ws+PS_, ws+RP1_, ws+SD_, ws+SS_, ws+SR1_, ws+X_, 0);

  // head 1
  k_gnp<256,128,128,32,2,128,1,1,1,1><<<dim3((N_NODES+31)/32,1),256,0,stream>>>(
      emb, flag, N_NODES, ws+TW_+32768, ws+TW_+49152, a21, 128L,
      ws+PD_, ws+PS_, ws+SD_, ws+SS_);
  k_gnp<256,128,128,64,2,128,0,0,1,1><<<dim3(4,1),256,0,stream>>>(
      rel, flag, 256, ws+TW_+81920, nullptr, a21, 128L,
      ws+RP1_, nullptr, ws+SR1_, nullptr);
  k_gath1<<<(N_NODES+3)/4,256,0,stream>>>(rowp, esrc, epak,
      ws+PD_, ws+PS_, ws+RP1_, ws+SD_, ws+SS_, ws+SR1_, ws+X_, 128);

  k_rel2<<<256,256,0,stream>>>(rel, W, flag, ws+R2_, d_out);

  // layer-2 weight prep: MFMA fragment-packed hi/lo bf16 [col][k] for d,s
  // (occupies float range [TW_, TW_+131072)) + fp32 [k][col] transpose for a_r
  bf16* wb = (bf16*)(ws + TW_);
  k_wfrag<<<256,256,0,stream>>>(aout, flag, 0L,   768L, 256, wb,        wb+65536);
  k_wfrag<<<256,256,0,stream>>>(aout, flag, 256L, 768L, 256, wb+131072, wb+196608);
  k_trF<<<256,256,0,stream>>>(aout, flag, 512L, 768L, 256, ws+TW_+131072);

  // layer-2 relation projection via scalar gnp (tiny)
  k_gnp<256,256,128,64,4,256,0,0,1,0><<<dim3(4,1),256,0,stream>>>(
      ws+R2_, flag, 256, ws+TW_+131072, nullptr, a2o, 0L,
      ws+RP2_, nullptr, ws+SR2_, nullptr);

  // layer-2 node projection: MFMA split-bf16 (dual + fused scores)
  k_gm2<<<(N_NODES+63)/64,256,0,stream>>>(
      ws+X_, N_NODES, wb, wb+65536, wb+131072, wb+196608,
      a2o, flag, ws+P2D_, ws+P2S_, ws+S2D_, ws+S2S_);

  // x dead now. We fp32 -> RP1_ (rp1 dead); eu -> X_ (x dead)
  k_cvtF<<<128,256,0,stream>>>(We, flag, 32768, ws+RP1_);
  k_mask<<<16,256,0,stream>>>(bi, ws+MK_);
  k_gnp<256,128,128,32,4,256,1,0,0,1><<<dim3((N_NODES+31)/32,1),256,0,stream>>>(
      emb, flag, N_NODES, ws+RP1_, nullptr, nullptr, 0L,
      ws+X_, nullptr, nullptr, nullptr);

  // layer-2 gather with fused final epilogue -> d_out
  k_gath2<<<(N_NODES+3)/4,256,0,stream>>>(rowp, esrc, epak,
      ws+P2D_, ws+P2S_, ws+RP2_, ws+S2D_, ws+S2S_, ws+SR2_,
      ws+X_, ws+MK_, flag, d_out);
}

// Round 10
// 903.604 us; speedup vs baseline: 1.3582x; 1.3582x over previous
//
#include <hip/hip_runtime.h>
#include <hip/hip_bf16.h>
#include <math.h>

#define N_NODES 50000
#define E1 300000
#define EN 30000
#define ETOT 330000

typedef __hip_bfloat16 bf16;
typedef __attribute__((ext_vector_type(8))) short s8v;   // 8 bf16 in 4 VGPRs
typedef __attribute__((ext_vector_type(4))) float f4v;   // MFMA accum

__device__ __forceinline__ float b2f(bf16 x){ return __bfloat162float(x); }
__device__ __forceinline__ bf16 f2b(float x){ return __float2bfloat16(x); }

__device__ __forceinline__ f4v mfma16(s8v a, s8v b, f4v c){
  return __builtin_amdgcn_mfma_f32_16x16x32_bf16(a, b, c, 0, 0, 0);
}

__device__ __forceinline__ float ldf(const void* p, long i, bool f32){
  return f32 ? ((const float*)p)[i] : b2f(((const bf16*)p)[i]);
}
__device__ __forceinline__ void stf(void* p, long i, float v, bool f32){
  if (f32) ((float*)p)[i] = v; else ((bf16*)p)[i] = f2b(v);
}
// packed 4-element store (16B fp32 / 8B bf16), elem must be multiple of 4
__device__ __forceinline__ void stv4(void* p, long elem, float a, float b,
                                     float c, float d, bool f32){
  if (f32){
    float4 t; t.x=a; t.y=b; t.z=c; t.w=d;
    *reinterpret_cast<float4*>((float*)p + elem) = t;
  } else {
    bf16 t[4] = {f2b(a), f2b(b), f2b(c), f2b(d)};
    *reinterpret_cast<uint2*>((bf16*)p + elem) = *reinterpret_cast<uint2*>(t);
  }
}

// Detect input dtype: flag=0 -> bf16, flag=1 -> fp32
__global__ void k_detect(const void* __restrict__ emb, int* __restrict__ flag){
  const unsigned short* h = (const unsigned short*)emb;
  int sane = 0;
  for (int i=0;i<128;i++){
    unsigned e = (h[i]>>7)&0xFFu;
    if (e>=112u && e<=143u) sane++;
  }
  *flag = (sane >= 112) ? 0 : 1;
}

// ---- CSR build (by dst), shared by all 3 edge passes ----
__global__ void k_hist(const int* __restrict__ el, const int* __restrict__ eln,
                       int* __restrict__ cnt){
  int i = blockIdx.x*blockDim.x + threadIdx.x;
  if (i < ETOT){
    int dst = (i < E1) ? el[i] : eln[i - E1];
    atomicAdd(cnt + dst, 1);
  }
}

__global__ __launch_bounds__(1024) void k_scan(const int* __restrict__ cnt,
                                               int* __restrict__ rowp,
                                               int* __restrict__ cur){
  __shared__ int part[1024];
  int t = threadIdx.x;
  const int CH = (N_NODES + 1023)/1024;
  int base = t*CH;
  int s = 0;
  for (int i=0;i<CH;i++){ int n = base+i; if (n < N_NODES) s += cnt[n]; }
  part[t] = s;
  __syncthreads();
  for (int o=1;o<1024;o<<=1){
    int u = (t>=o) ? part[t-o] : 0;
    __syncthreads();
    part[t] += u;
    __syncthreads();
  }
  int off = part[t] - s;
  for (int i=0;i<CH;i++){
    int n = base+i;
    if (n < N_NODES){ rowp[n] = off; cur[n] = off; off += cnt[n]; }
  }
  if (t==0) rowp[N_NODES] = ETOT;
}

__global__ void k_fill(const int* __restrict__ el, const int* __restrict__ et,
                       const int* __restrict__ eln, const int* __restrict__ etn,
                       int* __restrict__ cur, int* __restrict__ esrc,
                       int* __restrict__ epak){
  int i = blockIdx.x*blockDim.x + threadIdx.x;
  if (i >= ETOT) return;
  int dst, src, pk;
  if (i < E1){
    dst = el[i]; src = el[E1 + i];
    pk = et[i];
  } else {
    int e = i - E1;
    dst = eln[e]; src = eln[EN + e];
    pk = etn[2*e] | (etn[2*e+1]<<9) | (1<<18);
  }
  int pos = atomicAdd(cur + dst, 1);
  esrc[pos] = src; epak[pos] = pk;
}

// ---- gather layer-1 (fused fin1): one wave per dst node, float2 lanes ----
__global__ __launch_bounds__(256) void k_gath1(
    const int* __restrict__ rowp, const int* __restrict__ esrc,
    const int* __restrict__ epak,
    const float* __restrict__ pd, const float* __restrict__ ps,
    const float* __restrict__ rp,
    const float* __restrict__ sd, const float* __restrict__ ss,
    const float* __restrict__ sr,
    float* __restrict__ x, int hoff){
  int w = threadIdx.x >> 6, lane = threadIdx.x & 63;
  int n = blockIdx.x*4 + w;
  if (n >= N_NODES) return;
  const float2* ps2 = (const float2*)ps;
  const float2* rp2 = (const float2*)rp;
  float2 acc; acc.x = 0.f; acc.y = 0.f;
  float rs = 0.f;
  float sdn = sd[n];
  int b = rowp[n], e = rowp[n+1];
  for (int i=b;i<e;i++){
    int src = esrc[i], pk = epak[i];
    int t0 = pk & 511, t1 = (pk>>9)&511, has2 = (pk>>18)&1;
    float srv = sr[t0] + (has2 ? sr[t1] : 0.f);
    float score = sdn + ss[src] + srv;
    float lr = score > 0.f ? score : 0.2f*score;
    float wgt = expf(-lr);
    rs += wgt;
    float2 v  = ps2[(long)src*64 + lane];
    float2 r1 = rp2[(long)t0*64 + lane];
    v.x += r1.x; v.y += r1.y;
    if (has2){ float2 r2v = rp2[(long)t1*64 + lane]; v.x += r2v.x; v.y += r2v.y; }
    acc.x += wgt*v.x; acc.y += wgt*v.y;
  }
  float denom = (rs == 0.f) ? 1e-12f : rs;
  float2 pdv = ((const float2*)pd)[(long)n*64 + lane];
  float hr0 = rs*pdv.x + acc.x, hr1 = rs*pdv.y + acc.y;
  float h0 = hr0/denom; h0 = h0 > 0.f ? h0 : (expf(h0) - 1.f);
  float h1 = hr1/denom; h1 = h1 > 0.f ? h1 : (expf(h1) - 1.f);
  float2 o; o.x = h0; o.y = h1;
  *reinterpret_cast<float2*>(x + (long)n*256 + hoff + lane*2) = o;
}

// ---- gather layer-2 (fused final epilogue): float4 lanes ----
__global__ __launch_bounds__(256) void k_gath2(
    const int* __restrict__ rowp, const int* __restrict__ esrc,
    const int* __restrict__ epak,
    const float* __restrict__ p2d, const float* __restrict__ ps,
    const float* __restrict__ rp,
    const float* __restrict__ sd, const float* __restrict__ ss,
    const float* __restrict__ sr,
    const float* __restrict__ eu, const float* __restrict__ mask,
    const int* __restrict__ flag, void* __restrict__ out){
  bool f32 = flag[0] != 0;
  int w = threadIdx.x >> 6, lane = threadIdx.x & 63;
  int n = blockIdx.x*4 + w;
  if (n >= N_NODES) return;
  const float4* ps4 = (const float4*)ps;
  const float4* rp4 = (const float4*)rp;
  float4 acc; acc.x=acc.y=acc.z=acc.w=0.f;
  float rs = 0.f;
  float sdn = sd[n];
  int b = rowp[n], e = rowp[n+1];
  for (int i=b;i<e;i++){
    int src = esrc[i], pk = epak[i];
    int t0 = pk & 511, t1 = (pk>>9)&511, has2 = (pk>>18)&1;
    float srv = sr[t0] + (has2 ? sr[t1] : 0.f);
    float score = sdn + ss[src] + srv;
    float lr = score > 0.f ? score : 0.2f*score;
    float wgt = expf(-lr);
    rs += wgt;
    float4 v  = ps4[(long)src*64 + lane];
    float4 r1 = rp4[(long)t0*64 + lane];
    v.x += r1.x; v.y += r1.y; v.z += r1.z; v.w += r1.w;
    if (has2){
      float4 r2v = rp4[(long)t1*64 + lane];
      v.x += r2v.x; v.y += r2v.y; v.z += r2v.z; v.w += r2v.w;
    }
    acc.x += wgt*v.x; acc.y += wgt*v.y; acc.z += wgt*v.z; acc.w += wgt*v.w;
  }
  float denom = (rs == 0.f) ? 1e-12f : rs;
  float mk = mask[n];
  float4 pdv = ((const float4*)p2d)[(long)n*64 + lane];
  float4 euv = ((const float4*)eu)[(long)n*64 + lane];
  float av[4] = {acc.x, acc.y, acc.z, acc.w};
  float pv[4] = {pdv.x, pdv.y, pdv.z, pdv.w};
  float ev[4] = {euv.x, euv.y, euv.z, euv.w};
  float val[4], xl[4];
  float n1 = 0.f, n2 = 0.f;
  #pragma unroll
  for (int m=0;m<4;m++){
    float hr = rs*pv[m] + av[m];
    float xo = hr/denom; xo = xo > 0.f ? xo : (expf(xo) - 1.f);
    float l  = hr > 0.f ? hr : (expf(hr) - 1.f);
    float v  = ev[m] + mk*xo;
    val[m] = v; xl[m] = l;
    n1 += v*v; n2 += l*l;
  }
  #pragma unroll
  for (int o=32;o>0;o>>=1){ n1 += __shfl_xor(n1,o); n2 += __shfl_xor(n2,o); }
  float i1 = 1.f/fmaxf(sqrtf(n1), 1e-12f);
  float i2 = 1.f/fmaxf(sqrtf(n2), 1e-12f);
  stv4(out, (long)n*256 + lane*4,
       val[0]*i1, val[1]*i1, val[2]*i1, val[3]*i1, f32);
  stv4(out, 12865536L + (long)n*256 + lane*4,
       xl[0]*i2, xl[1]*i2, xl[2]*i2, xl[3]*i2, f32);
}

// out_relation_1 = rel @ W  (fp32 copy to ws + dual-dtype output at element offset)
__global__ void k_rel2(const void* __restrict__ rel, const void* __restrict__ W,
                       const int* __restrict__ flag,
                       float* __restrict__ r2, void* __restrict__ out){
  bool f32 = flag[0] != 0;
  int t = blockIdx.x, j = threadIdx.x;   // 256 threads
  __shared__ float rs_[128];
  if (j < 128) rs_[j] = ldf(rel, (long)t*128 + j, f32);
  __syncthreads();
  float acc = 0.f;
  #pragma unroll 4
  for (int k=0;k<128;k++) acc += rs_[k]*ldf(W, (long)k*256 + j, f32);
  r2[(long)t*256+j] = acc;
  stf(out, 12800000L + (long)t*256 + j, acc, f32);
}

// Transpose weight block to fp32 [k][J]: dst[k*J+j] = src[bias + j*jstride + k]
__global__ void k_trF(const void* __restrict__ src, const int* __restrict__ flag,
                      long bias, long jstride, int J, float* __restrict__ dst){
  bool f32 = flag[0] != 0;
  int k = blockIdx.x, j = threadIdx.x;
  dst[(long)k*J + j] = ldf(src, bias + (long)j*jstride + k, f32);
}

// Weight fragment pack for MFMA, PACKED IN PER-LANE FRAGMENT ORDER so a
// wave's B-frag load is one contiguous 1KB read:
//   packed[((ct*8+kb)*64 + ln)*8 + j] = w[col=ct*16+(ln&15)][k=kb*32+(ln>>4)*8+j]
// hi = bf16(w), lo = bf16(w - float(hi)).  grid 128 (ct*8+kb), block 512.
__global__ __launch_bounds__(512) void k_wfrag2(
    const void* __restrict__ src, const int* __restrict__ flag,
    long bias, long jstride,
    bf16* __restrict__ whi, bf16* __restrict__ wlo){
  bool f32 = flag[0] != 0;
  int b = blockIdx.x;            // b = ct*8 + kb
  int ct = b >> 3, kb = b & 7;
  int t = threadIdx.x;
  int ln = t >> 3, j = t & 7;
  int col = ct*16 + (ln & 15);
  int k   = kb*32 + (ln >> 4)*8 + j;
  float w = ldf(src, bias + (long)col*jstride + k, f32);
  bf16 h = f2b(w);
  long o = ((long)b*64 + ln)*8 + j;
  whi[o] = h;
  wlo[o] = f2b(w - b2f(h));
}

// Convert-only (no transpose) to fp32: dst[i] = src[i]
__global__ void k_cvtF(const void* __restrict__ src, const int* __restrict__ flag,
                       int n, float* __restrict__ dst){
  bool f32 = flag[0] != 0;
  int i = blockIdx.x*blockDim.x + threadIdx.x;
  if (i < n) dst[i] = ldf(src, i, f32);
}

// ---- MFMA layer-2 node projection v2 (split-bf16, 3-term) ----
// BM=32 rows/block (LDS 33KB -> ~4 blocks/CU). Waves split COLUMNS: wave wv
// owns col-tiles wv*4..wv*4+3 (64 cols) for BOTH row-tiles -> each block
// reads the 512KB weight set exactly once, via fully-coalesced packed
// fragments (k_wfrag2 order). Per kb: 4 ds_read_b128 + 16 coalesced 16B
// weight loads + 48 MFMAs. Scores combined across waves through LDS.
// Layouts identical to R9 (verified passing): C/D col=lane&15,
// row=(lane>>4)*4+r; A row=lane&15, k=(lane>>4)*8+j.
__global__ __launch_bounds__(256) void k_gm2(
    const float* __restrict__ X, int N,
    const bf16* __restrict__ whd, const bf16* __restrict__ wld,
    const bf16* __restrict__ whs, const bf16* __restrict__ wls,
    const void* __restrict__ a2, const int* __restrict__ flag,
    float* __restrict__ O1, float* __restrict__ O2,
    float* __restrict__ s1, float* __restrict__ s2){
  __shared__ __align__(16) bf16 xhi[32*256];
  __shared__ __align__(16) bf16 xlo[32*256];
  __shared__ float sred1[32][4];
  __shared__ float sred2[32][4];
  int t = threadIdx.x, wv = t>>6, ln = t&63;
  int cl = ln & 15, rg = ln >> 4;
  int n0 = blockIdx.x*32;

  // stage X rows, hi/lo split, XOR-swizzled ((row&7)<<4 on byte addr)
  for (int i = t; i < 32*64; i += 256){
    int row = i >> 6, kq = i & 63;
    int n = n0 + row;
    float4 v; v.x=v.y=v.z=v.w=0.f;
    if (n < N) v = *reinterpret_cast<const float4*>(X + (long)n*256 + kq*4);
    bf16 h[4], l[4];
    h[0]=f2b(v.x); l[0]=f2b(v.x-b2f(h[0]));
    h[1]=f2b(v.y); l[1]=f2b(v.y-b2f(h[1]));
    h[2]=f2b(v.z); l[2]=f2b(v.z-b2f(h[2]));
    h[3]=f2b(v.w); l[3]=f2b(v.w-b2f(h[3]));
    long byo = ((long)row*512 + kq*8) ^ ((row&7)<<4);
    *reinterpret_cast<uint2*>(reinterpret_cast<char*>(xhi)+byo) =
        *reinterpret_cast<const uint2*>(h);
    *reinterpret_cast<uint2*>(reinterpret_cast<char*>(xlo)+byo) =
        *reinterpret_cast<const uint2*>(l);
  }
  __syncthreads();

  const char* xh = reinterpret_cast<const char*>(xhi);
  const char* xl = reinterpret_cast<const char*>(xlo);

  f4v accd[2][4], accs[2][4];
  const f4v zf = {0.f,0.f,0.f,0.f};
  #pragma unroll
  for (int rt=0; rt<2; ++rt)
    #pragma unroll
    for (int c=0; c<4; ++c){ accd[rt][c]=zf; accs[rt][c]=zf; }

  #pragma unroll 1
  for (int kb=0; kb<8; ++kb){
    s8v ah[2], al[2];
    #pragma unroll
    for (int rt=0; rt<2; ++rt){
      long arow = rt*16 + cl;
      long byo = (arow*512 + kb*64 + rg*16) ^ ((arow&7)<<4);
      ah[rt] = *reinterpret_cast<const s8v*>(xh + byo);
      al[rt] = *reinterpret_cast<const s8v*>(xl + byo);
    }
    #pragma unroll
    for (int c=0; c<4; ++c){
      int ct = wv*4 + c;
      long wo = ((long)(ct*8 + kb)*64 + ln)*8;
      s8v bh = *reinterpret_cast<const s8v*>((const void*)(whd + wo));
      s8v bl = *reinterpret_cast<const s8v*>((const void*)(wld + wo));
      s8v sh = *reinterpret_cast<const s8v*>((const void*)(whs + wo));
      s8v sl = *reinterpret_cast<const s8v*>((const void*)(wls + wo));
      #pragma unroll
      for (int rt=0; rt<2; ++rt){
        accd[rt][c] = mfma16(ah[rt], bh, accd[rt][c]);
        accd[rt][c] = mfma16(ah[rt], bl, accd[rt][c]);
        accd[rt][c] = mfma16(al[rt], bh, accd[rt][c]);
        accs[rt][c] = mfma16(ah[rt], sh, accs[rt][c]);
        accs[rt][c] = mfma16(ah[rt], sl, accs[rt][c]);
        accs[rt][c] = mfma16(al[rt], sh, accs[rt][c]);
      }
    }
  }

  // epilogue: O-writes + fused scores (per-wave partials over 64 cols)
  bool af32 = flag[0] != 0;
  float p1[2][4], p2[2][4];
  #pragma unroll
  for (int rt=0; rt<2; ++rt)
    #pragma unroll
    for (int r=0; r<4; ++r){ p1[rt][r]=0.f; p2[rt][r]=0.f; }

  #pragma unroll
  for (int c=0; c<4; ++c){
    int col = (wv*4+c)*16 + cl;
    float a2v = ldf(a2, col, af32);
    #pragma unroll
    for (int rt=0; rt<2; ++rt)
      #pragma unroll
      for (int r=0; r<4; ++r){
        p1[rt][r] += accd[rt][c][r]*a2v;
        p2[rt][r] += accs[rt][c][r]*a2v;
      }
  }

  #pragma unroll
  for (int rt=0; rt<2; ++rt){
    #pragma unroll
    for (int r=0; r<4; ++r){
      int n = n0 + rt*16 + rg*4 + r;
      if (n < N){
        #pragma unroll
        for (int c=0; c<4; ++c){
          int col = (wv*4+c)*16 + cl;
          O1[(long)n*256 + col] = accd[rt][c][r];
          O2[(long)n*256 + col] = accs[rt][c][r];
        }
      }
    }
  }

  #pragma unroll
  for (int o=1; o<16; o<<=1){
    #pragma unroll
    for (int rt=0; rt<2; ++rt)
      #pragma unroll
      for (int r=0; r<4; ++r){
        p1[rt][r] += __shfl_xor(p1[rt][r], o);
        p2[rt][r] += __shfl_xor(p2[rt][r], o);
      }
  }
  if (cl == 0){
    #pragma unroll
    for (int rt=0; rt<2; ++rt)
      #pragma unroll
      for (int r=0; r<4; ++r){
        int row = rt*16 + rg*4 + r;
        sred1[row][wv] = p1[rt][r];
        sred2[row][wv] = p2[rt][r];
      }
  }
  __syncthreads();
  if (t < 32){
    int n = n0 + t;
    if (n < N){
      s1[n] = sred1[t][0]+sred1[t][1]+sred1[t][2]+sred1[t][3];
      s2[n] = sred2[t][0]+sred2[t][1]+sred2[t][2]+sred2[t][3];
    }
  }
}

// Unified scalar GEMM kernel (layer-1 / relation / entup paths)
template<int NT, int K, int KT, int BM, int NCOL, int COLS_TOT,
         int NORM, int DUAL, int SCORE, int XDUAL>
__global__ __launch_bounds__(NT) void k_gnp(
    const void* __restrict__ X, const int* __restrict__ flag, int N,
    const float* __restrict__ WT1, const float* __restrict__ WT2,
    const void* __restrict__ a2, long a2bias,
    float* __restrict__ O1, float* __restrict__ O2,
    float* __restrict__ s1, float* __restrict__ s2){
  const int COLS  = 64*NCOL;
  const int WAVES = NT/64;
  const int RW    = BM/WAVES;
  __shared__ __align__(16) float xs[BM][KT];
  __shared__ float rsc[BM];
  int t = threadIdx.x;
  int wv = t >> 6, ln = t & 63;
  int r0 = wv * RW;
  int n0 = blockIdx.x * BM;
  int coff = blockIdx.y * COLS;
  bool xf32 = XDUAL ? (flag[0] != 0) : true;

  float a1c[RW][NCOL], a2c[RW][NCOL];
  #pragma unroll
  for (int m=0;m<RW;m++)
    #pragma unroll
    for (int c=0;c<NCOL;c++){ a1c[m][c]=0.f; a2c[m][c]=0.f; }

  for (int kt0 = 0; kt0 < K; kt0 += KT){
    if (xf32){
      const int KQ = KT/4;
      for (int idx = t; idx < BM*KQ; idx += NT){
        int m = idx / KQ, kq = idx - m*KQ;
        int n = n0 + m;
        float4 v; v.x=v.y=v.z=v.w=0.f;
        if (n < N)
          v = *reinterpret_cast<const float4*>((const float*)X + (long)n*K + kt0 + kq*4);
        *reinterpret_cast<float4*>(&xs[m][kq*4]) = v;
      }
    } else {
      for (int idx = t; idx < BM*KT; idx += NT){
        int m = idx / KT, k = idx - m*KT;
        int n = n0 + m;
        xs[m][k] = (n < N) ? b2f(((const bf16*)X)[(long)n*K + kt0 + k]) : 0.f;
      }
    }
    __syncthreads();

    if (NORM){
      const int NPR = NT / BM;
      int r = t / NPR, l = t - r*NPR;
      float ssq = 0.f;
      #pragma unroll
      for (int k = l; k < KT; k += NPR){ float v = xs[r][k]; ssq += v*v; }
      #pragma unroll
      for (int o = NPR>>1; o > 0; o >>= 1) ssq += __shfl_xor(ssq, o);
      if (l == 0) rsc[r] = 1.f / fmaxf(sqrtf(ssq), 1e-12f);
      __syncthreads();
      for (int idx = t; idx < BM*KT; idx += NT){
        int m = idx / KT, k = idx - m*KT;
        xs[m][k] *= rsc[m];
      }
      __syncthreads();
    }

    #pragma unroll 1
    for (int k0=0;k0<KT;k0+=4){
      float w1v[4][NCOL], w2v[4][NCOL];
      #pragma unroll
      for (int i=0;i<4;i++){
        const float* p1 = WT1 + (long)(kt0+k0+i)*COLS_TOT + coff + ln*NCOL;
        if constexpr (NCOL==4){
          float4 v = *reinterpret_cast<const float4*>(p1);
          w1v[i][0]=v.x; w1v[i][1]=v.y; w1v[i][2]=v.z; w1v[i][3]=v.w;
        } else {
          float2 v = *reinterpret_cast<const float2*>(p1);
          w1v[i][0]=v.x; w1v[i][1]=v.y;
        }
        if (DUAL){
          const float* p2 = WT2 + (long)(kt0+k0+i)*COLS_TOT + coff + ln*NCOL;
          if constexpr (NCOL==4){
            float4 v = *reinterpret_cast<const float4*>(p2);
            w2v[i][0]=v.x; w2v[i][1]=v.y; w2v[i][2]=v.z; w2v[i][3]=v.w;
          } else {
            float2 v = *reinterpret_cast<const float2*>(p2);
            w2v[i][0]=v.x; w2v[i][1]=v.y;
          }
        }
      }
      #pragma unroll
      for (int m=0;m<RW;m++){
        float4 xv = *reinterpret_cast<const float4*>(&xs[r0+m][k0]);
        #pragma unroll
        for (int c=0;c<NCOL;c++){
          a1c[m][c] += xv.x*w1v[0][c] + xv.y*w1v[1][c] + xv.z*w1v[2][c] + xv.w*w1v[3][c];
          if (DUAL)
            a2c[m][c] += xv.x*w2v[0][c] + xv.y*w2v[1][c] + xv.z*w2v[2][c] + xv.w*w2v[3][c];
        }
      }
    }
    __syncthreads();
  }

  #pragma unroll
  for (int m=0;m<RW;m++){
    int n = n0 + r0 + m;
    if (n < N){
      float* o1 = O1 + (long)n*COLS_TOT + coff + ln*NCOL;
      if constexpr (NCOL==4){
        float4 v; v.x=a1c[m][0]; v.y=a1c[m][1]; v.z=a1c[m][2]; v.w=a1c[m][3];
        *reinterpret_cast<float4*>(o1) = v;
      } else {
        float2 v; v.x=a1c[m][0]; v.y=a1c[m][1];
        *reinterpret_cast<float2*>(o1) = v;
      }
      if (DUAL){
        float* o2 = O2 + (long)n*COLS_TOT + coff + ln*NCOL;
        if constexpr (NCOL==4){
          float4 v; v.x=a2c[m][0]; v.y=a2c[m][1]; v.z=a2c[m][2]; v.w=a2c[m][3];
          *reinterpret_cast<float4*>(o2) = v;
        } else {
          float2 v; v.x=a2c[m][0]; v.y=a2c[m][1];
          *reinterpret_cast<float2*>(o2) = v;
        }
      }
    }
  }

  if (SCORE){
    bool af32 = flag[0] != 0;
    float a2v[NCOL];
    #pragma unroll
    for (int c=0;c<NCOL;c++) a2v[c] = ldf(a2, a2bias + coff + ln*NCOL + c, af32);
    long soff = (long)blockIdx.y * N;
    #pragma unroll
    for (int m=0;m<RW;m++){
      float v1 = 0.f, v2 = 0.f;
      #pragma unroll
      for (int c=0;c<NCOL;c++){
        v1 += a1c[m][c]*a2v[c];
        if (DUAL) v2 += a2c[m][c]*a2v[c];
      }
      #pragma unroll
      for (int o=32;o>0;o>>=1){
        v1 += __shfl_down(v1,o);
        if (DUAL) v2 += __shfl_down(v2,o);
      }
      int n = n0 + r0 + m;
      if (ln==0 && n < N){
        s1[soff + n] = v1;
        if (DUAL) s2[soff + n] = v2;
      }
    }
  }
}

__global__ void k_mask(const int* __restrict__ bi, float* __restrict__ mask){
  int i = blockIdx.x*blockDim.x + threadIdx.x;
  if (i < 4096) mask[bi[i*3 + 2]] = 1.f;
}

extern "C" void kernel_launch(void* const* d_in, const int* in_sizes, int n_in,
                              void* d_out, int out_size, void* d_ws, size_t ws_size,
                              hipStream_t stream) {
  const void* emb = d_in[0];
  const void* rel = d_in[1];
  const void* a1b = d_in[2];
  const void* a21 = d_in[3];
  const void* W   = d_in[4];
  const void* aout= d_in[5];
  const void* a2o = d_in[6];
  const void* We  = d_in[7];
  const int* bi   = (const int*)d_in[8];
  const int* el   = (const int*)d_in[9];
  const int* et   = (const int*)d_in[10];
  const int* eln  = (const int*)d_in[11];
  const int* etn  = (const int*)d_in[12];
  float* ws = (float*)d_ws;

  const size_t PD_=0, PS_=6400000;
  const size_t P2D_=0;
  const size_t CNT_=12800000, ROWP_=12860000, ESRC_=12920000, EPAK_=13260000;
  const size_t TW_=19200000;
  const size_t X_=25600000;        // x, later eu
  const size_t P2S_=38400000;
  const size_t SD_=51250000, SS_=51300000, S2D_=51350000,
               S2S_=51400000, MK_=51500000,
               RP1_=51550000, SR1_=51590000, R2_=51600000, RP2_=51670000,
               SR2_=51740000, FLAG_=51750000;
  int* flag = (int*)(ws + FLAG_);
  int* cnt  = (int*)(ws + CNT_);
  int* rowp = (int*)(ws + ROWP_);
  int* esrc = (int*)(ws + ESRC_);
  int* epak = (int*)(ws + EPAK_);

  k_detect<<<1,1,0,stream>>>(emb, flag);

  hipMemsetAsync(ws+MK_,  0, (size_t)50000*sizeof(float), stream);
  hipMemsetAsync(cnt,     0, (size_t)50000*sizeof(int), stream);

  // CSR build (once; shared by all 3 edge passes)
  k_hist<<<(ETOT+255)/256,256,0,stream>>>(el, eln, cnt);
  k_scan<<<1,1024,0,stream>>>(cnt, rowp, cnt);
  k_fill<<<(ETOT+255)/256,256,0,stream>>>(el, et, eln, etn, cnt, esrc, epak);

  // transpose the 6 layer-1 weight blocks to fp32 [k][128]
  k_trF<<<128,128,0,stream>>>(a1b, flag, 0L,          384L, 128, ws+TW_);          // h0 a_d
  k_trF<<<128,128,0,stream>>>(a1b, flag, 128L,        384L, 128, ws+TW_+16384);    // h0 a_s
  k_trF<<<128,128,0,stream>>>(a1b, flag, 49152L,      384L, 128, ws+TW_+32768);    // h1 a_d
  k_trF<<<128,128,0,stream>>>(a1b, flag, 49152L+128L, 384L, 128, ws+TW_+49152);    // h1 a_s
  k_trF<<<128,128,0,stream>>>(a1b, flag, 256L,        384L, 128, ws+TW_+65536);    // h0 a_r
  k_trF<<<128,128,0,stream>>>(a1b, flag, 49152L+256L, 384L, 128, ws+TW_+81920);    // h1 a_r

  // head 0: fused norm + dual projection + score; rel-proj via gnp; gather
  k_gnp<256,128,128,32,2,128,1,1,1,1><<<dim3((N_NODES+31)/32,1),256,0,stream>>>(
      emb, flag, N_NODES, ws+TW_, ws+TW_+16384, a21, 0L,
      ws+PD_, ws+PS_, ws+SD_, ws+SS_);
  k_gnp<256,128,128,64,2,128,0,0,1,1><<<dim3(4,1),256,0,stream>>>(
      rel, flag, 256, ws+TW_+65536, nullptr, a21, 0L,
      ws+RP1_, nullptr, ws+SR1_, nullptr);
  k_gath1<<<(N_NODES+3)/4,256,0,stream>>>(rowp, esrc, epak,
      ws+PD_, ws+PS_, ws+RP1_, ws+SD_, ws+SS_, ws+SR1_, ws+X_, 0);

  // head 1
  k_gnp<256,128,128,32,2,128,1,1,1,1><<<dim3((N_NODES+31)/32,1),256,0,stream>>>(
      emb, flag, N_NODES, ws+TW_+32768, ws+TW_+49152, a21, 128L,
      ws+PD_, ws+PS_, ws+SD_, ws+SS_);
  k_gnp<256,128,128,64,2,128,0,0,1,1><<<dim3(4,1),256,0,stream>>>(
      rel, flag, 256, ws+TW_+81920, nullptr, a21, 128L,
      ws+RP1_, nullptr, ws+SR1_, nullptr);
  k_gath1<<<(N_NODES+3)/4,256,0,stream>>>(rowp, esrc, epak,
      ws+PD_, ws+PS_, ws+RP1_, ws+SD_, ws+SS_, ws+SR1_, ws+X_, 128);

  k_rel2<<<256,256,0,stream>>>(rel, W, flag, ws+R2_, d_out);

  // layer-2 weight prep: fragment-packed hi/lo bf16 (coalesced order) for d,s
  // + fp32 [k][col] transpose for a_r
  bf16* wb = (bf16*)(ws + TW_);
  k_wfrag2<<<128,512,0,stream>>>(aout, flag, 0L,   768L, wb,        wb+65536);
  k_wfrag2<<<128,512,0,stream>>>(aout, flag, 256L, 768L, wb+131072, wb+196608);
  k_trF<<<256,256,0,stream>>>(aout, flag, 512L, 768L, 256, ws+TW_+131072);

  // layer-2 relation projection via scalar gnp (tiny)
  k_gnp<256,256,128,64,4,256,0,0,1,0><<<dim3(4,1),256,0,stream>>>(
      ws+R2_, flag, 256, ws+TW_+131072, nullptr, a2o, 0L,
      ws+RP2_, nullptr, ws+SR2_, nullptr);

  // layer-2 node projection: MFMA split-bf16 v2 (dual + fused scores)
  k_gm2<<<(N_NODES+31)/32,256,0,stream>>>(
      ws+X_, N_NODES, wb, wb+65536, wb+131072, wb+196608,
      a2o, flag, ws+P2D_, ws+P2S_, ws+S2D_, ws+S2S_);

  // x dead now. We fp32 -> RP1_ (rp1 dead); eu -> X_ (x dead)
  k_cvtF<<<128,256,0,stream>>>(We, flag, 32768, ws+RP1_);
  k_mask<<<16,256,0,stream>>>(bi, ws+MK_);
  k_gnp<256,128,128,32,4,256,1,0,0,1><<<dim3((N_NODES+31)/32,1),256,0,stream>>>(
      emb, flag, N_NODES, ws+RP1_, nullptr, nullptr, 0L,
      ws+X_, nullptr, nullptr, nullptr);

  // layer-2 gather with fused final epilogue -> d_out
  k_gath2<<<(N_NODES+3)/4,256,0,stream>>>(rowp, esrc, epak,
      ws+P2D_, ws+P2S_, ws+RP2_, ws+S2D_, ws+S2S_, ws+SR2_,
      ws+X_, ws+MK_, flag, d_out);
}